// Round 1
// baseline (568.009 us; speedup 1.0000x reference)
//
#include <hip/hip_runtime.h>

#define N_PTS 100000
#define NK 27
#define TOTAL (N_PTS * 64)          // 6400000
#define NB_CONV 782                 // ceil(100000 / 128)

typedef short bf16x8 __attribute__((ext_vector_type(8)));   // 8 bf16 in 4 VGPRs
typedef float f32x4 __attribute__((ext_vector_type(4)));
typedef unsigned short u16x8 __attribute__((ext_vector_type(8)));

__device__ __forceinline__ unsigned short f2bf(float f) {
    unsigned u = __builtin_bit_cast(unsigned, f);
    u += 0x7fffu + ((u >> 16) & 1u);           // round-to-nearest-even
    return (unsigned short)(u >> 16);
}

// ---------------- cast feats -> bf16, plus zeroed pad row at index N_PTS ----------------
__global__ void cast_in_k(const float* __restrict__ feats, unsigned short* __restrict__ xb) {
    int t = blockIdx.x * 256 + threadIdx.x;
    if (t >= (N_PTS + 1) * 8) return;          // 8-elem chunks per 64-ch row
    int i = t * 8;
    u16x8 o;
    if (i < TOTAL) {
        f32x4 v0 = ((const f32x4*)(feats + i))[0];
        f32x4 v1 = ((const f32x4*)(feats + i))[1];
#pragma unroll
        for (int j = 0; j < 4; ++j) { o[j] = f2bf(v0[j]); o[4 + j] = f2bf(v1[j]); }
    } else {
#pragma unroll
        for (int j = 0; j < 8; ++j) o[j] = 0;
    }
    *(u16x8*)(xb + i) = o;
}

// ---------------- pack W [4][27][64][64] f32 -> bf16 MFMA-B-fragment order ----------------
// Wp layout: [conv][k][kk][cb][lane][8] ; fragment elem j is B[k = kk*32+(lane>>4)*8+j, col = cb*16+(lane&15)]
__global__ void pack_w_k(const float* __restrict__ W, unsigned short* __restrict__ Wp) {
    int o = blockIdx.x * 256 + threadIdx.x;
    if (o >= 4 * NK * 4096) return;
    int conv = o / (NK * 4096);
    int r = o - conv * (NK * 4096);
    int k = r >> 12;
    int r2 = r & 4095;
    int frag = r2 >> 9;                        // kk*4 + cb
    int kk = frag >> 2, cb = frag & 3;
    int lane = (r2 >> 3) & 63;
    int j = r2 & 7;
    int c = kk * 32 + (lane >> 4) * 8 + j;
    int d = cb * 16 + (lane & 15);
    Wp[o] = f2bf(W[(size_t)(conv * NK + k) * 4096 + c * 64 + d]);
}

// ---------------- gather-GEMM conv: y[n,d] = sum_k sum_c xb[nbrs[n,k],c] * W[k,c,d] ----------------
// block = 256 thr = 4 waves; wave owns 32 rows x 64 cols; fused per-channel sum/sumsq partials.
__global__ __launch_bounds__(256) void conv_k(
    const unsigned short* __restrict__ xb,     // [N_PTS+1][64] bf16
    const int* __restrict__ nbrs,              // [N_PTS][27]
    const unsigned short* __restrict__ Wp,     // packed fragments for this conv
    float* __restrict__ y,                     // [N_PTS][64] f32
    float* __restrict__ partials)              // [NB_CONV][128]
{
    const int tid = threadIdx.x;
    const int lane = tid & 63;
    const int wave = tid >> 6;
    const int l15 = lane & 15;
    const int lgrp = lane >> 4;
    const int wave_row = blockIdx.x * 128 + wave * 32;

    const int r0 = wave_row + l15;
    const int r1 = r0 + 16;
    const bool ok0 = r0 < N_PTS, ok1 = r1 < N_PTS;
    const long n0 = (long)r0 * NK;
    const long n1 = (long)r1 * NK;

    f32x4 acc[2][4];
#pragma unroll
    for (int m = 0; m < 2; ++m)
#pragma unroll
        for (int cb = 0; cb < 4; ++cb) acc[m][cb] = (f32x4)0.f;

    const bf16x8* wp = (const bf16x8*)Wp;

#pragma unroll 2
    for (int k = 0; k < NK; ++k) {
        int i0 = ok0 ? nbrs[n0 + k] : N_PTS;   // N_PTS -> zero pad row
        int i1 = ok1 ? nbrs[n1 + k] : N_PTS;
        const bf16x8* p0 = (const bf16x8*)(xb + (size_t)i0 * 64);
        const bf16x8* p1 = (const bf16x8*)(xb + (size_t)i1 * 64);
        // A fragments: lane reads 16B chunk (kk*4 + lgrp) of its row
        bf16x8 a00 = p0[lgrp];                 // kk = 0 (c 0..31)
        bf16x8 a01 = p0[4 + lgrp];             // kk = 1 (c 32..63)
        bf16x8 a10 = p1[lgrp];
        bf16x8 a11 = p1[4 + lgrp];
        const bf16x8* wk = wp + (size_t)k * 512 + lane;   // frag f at wk[f*64]
#pragma unroll
        for (int cb = 0; cb < 4; ++cb) {
            bf16x8 b = wk[cb * 64];
            acc[0][cb] = __builtin_amdgcn_mfma_f32_16x16x32_bf16(a00, b, acc[0][cb], 0, 0, 0);
            acc[1][cb] = __builtin_amdgcn_mfma_f32_16x16x32_bf16(a10, b, acc[1][cb], 0, 0, 0);
        }
#pragma unroll
        for (int cb = 0; cb < 4; ++cb) {
            bf16x8 b = wk[(4 + cb) * 64];
            acc[0][cb] = __builtin_amdgcn_mfma_f32_16x16x32_bf16(a01, b, acc[0][cb], 0, 0, 0);
            acc[1][cb] = __builtin_amdgcn_mfma_f32_16x16x32_bf16(a11, b, acc[1][cb], 0, 0, 0);
        }
    }

    // ---- store y (D layout: col = lane&15, row = (lane>>4)*4 + reg) ----
#pragma unroll
    for (int m = 0; m < 2; ++m) {
        int rb = wave_row + m * 16 + lgrp * 4;
#pragma unroll
        for (int r = 0; r < 4; ++r) {
            if (rb + r < N_PTS) {
                float* yr = y + (size_t)(rb + r) * 64 + l15;
#pragma unroll
                for (int cb = 0; cb < 4; ++cb) yr[cb * 16] = acc[m][cb][r];
            }
        }
    }

    // ---- fused per-channel partial sum / sumsq ----
    __shared__ float sred[4][128];
#pragma unroll
    for (int cb = 0; cb < 4; ++cb) {
        float s = 0.f, s2 = 0.f;
#pragma unroll
        for (int m = 0; m < 2; ++m)
#pragma unroll
            for (int r = 0; r < 4; ++r) {
                float v = acc[m][cb][r];
                s += v; s2 += v * v;
            }
        s += __shfl_xor(s, 16); s += __shfl_xor(s, 32);
        s2 += __shfl_xor(s2, 16); s2 += __shfl_xor(s2, 32);
        if (lane < 16) {
            sred[wave][cb * 16 + l15] = s;
            sred[wave][64 + cb * 16 + l15] = s2;
        }
    }
    __syncthreads();
    if (tid < 128) {
        float p = sred[0][tid] + sred[1][tid] + sred[2][tid] + sred[3][tid];
        partials[(size_t)blockIdx.x * 128 + tid] = p;
    }
}

// ---------------- BN finalize: scale/shift from partials ----------------
__global__ void bn_fin_k(const float* __restrict__ partials,
                         const float* __restrict__ gamma,
                         const float* __restrict__ beta,
                         float* __restrict__ scsh) {
    int t = threadIdx.x;                       // 128 threads
    float s = 0.f;
    for (int w = 0; w < NB_CONV; ++w) s += partials[w * 128 + t];
    __shared__ float sm[128];
    sm[t] = s;
    __syncthreads();
    if (t < 64) {
        const float invN = 1.0f / (float)N_PTS;
        float mu = sm[t] * invN;
        float var = sm[64 + t] * invN - mu * mu;
        float sc = gamma[t] * rsqrtf(var + 1e-4f);
        scsh[t] = sc;
        scsh[64 + t] = beta[t] - mu * sc;
    }
}

// ---------------- BN + ReLU -> bf16 (input to next conv) ----------------
__global__ void bn_relu_cast_k(const float* __restrict__ y, const float* __restrict__ scsh,
                               unsigned short* __restrict__ xb) {
    int t = blockIdx.x * 256 + threadIdx.x;
    if (t >= TOTAL / 8) return;
    int i = t * 8;
    int c0 = i & 63;
    f32x4 v0 = ((const f32x4*)(y + i))[0];
    f32x4 v1 = ((const f32x4*)(y + i))[1];
    u16x8 o;
#pragma unroll
    for (int j = 0; j < 4; ++j) {
        o[j]     = f2bf(fmaxf(v0[j] * scsh[c0 + j]     + scsh[64 + c0 + j],     0.f));
        o[4 + j] = f2bf(fmaxf(v1[j] * scsh[c0 + 4 + j] + scsh[64 + c0 + 4 + j], 0.f));
    }
    *(u16x8*)(xb + i) = o;
}

// ---------------- BN + residual + ReLU -> f32 out (+ bf16 for next conv) ----------------
__global__ void bn_add_relu_k(const float* __restrict__ y, const float* __restrict__ scsh,
                              const float* __restrict__ res, float* __restrict__ xout,
                              unsigned short* __restrict__ xb, int writeBf) {
    int t = blockIdx.x * 256 + threadIdx.x;
    if (t >= TOTAL / 8) return;
    int i = t * 8;
    int c0 = i & 63;
    f32x4 v0 = ((const f32x4*)(y + i))[0];
    f32x4 v1 = ((const f32x4*)(y + i))[1];
    f32x4 q0 = ((const f32x4*)(res + i))[0];
    f32x4 q1 = ((const f32x4*)(res + i))[1];
    f32x4 o0, o1;
#pragma unroll
    for (int j = 0; j < 4; ++j) {
        o0[j] = fmaxf(v0[j] * scsh[c0 + j]     + scsh[64 + c0 + j]     + q0[j], 0.f);
        o1[j] = fmaxf(v1[j] * scsh[c0 + 4 + j] + scsh[64 + c0 + 4 + j] + q1[j], 0.f);
    }
    ((f32x4*)(xout + i))[0] = o0;
    ((f32x4*)(xout + i))[1] = o1;
    if (writeBf) {
        u16x8 o;
#pragma unroll
        for (int j = 0; j < 4; ++j) { o[j] = f2bf(o0[j]); o[4 + j] = f2bf(o1[j]); }
        *(u16x8*)(xb + i) = o;
    }
}

extern "C" void kernel_launch(void* const* d_in, const int* in_sizes, int n_in,
                              void* d_out, int out_size, void* d_ws, size_t ws_size,
                              hipStream_t stream) {
    const float* feats = (const float*)d_in[0];
    const int*   nbrs  = (const int*)d_in[1];
    const float* W     = (const float*)d_in[2];
    const float* gamma = (const float*)d_in[3];
    const float* beta  = (const float*)d_in[4];
    float* out = (float*)d_out;

    char* ws = (char*)d_ws;
    unsigned short* xb       = (unsigned short*)ws;            // 12,800,128 B
    float*          y        = (float*)(ws + 12800512);        // 25,600,000 B
    unsigned short* Wp       = (unsigned short*)(ws + 38401024); // 884,736 B
    float*          partials = (float*)(ws + 39286272);        // 400,384 B
    float*          scsh     = (float*)(ws + 39686912);        // 512 B

    dim3 b256(256);
    cast_in_k<<<((N_PTS + 1) * 8 + 255) / 256, b256, 0, stream>>>(feats, xb);
    pack_w_k<<<(4 * NK * 4096) / 256, b256, 0, stream>>>(W, Wp);

    const int appl_blocks = (TOTAL / 8) / 256;  // 3125
    for (int blk = 0; blk < 2; ++blk) {
        int c0 = blk * 2, c1 = blk * 2 + 1;
        conv_k<<<NB_CONV, b256, 0, stream>>>(xb, nbrs, Wp + (size_t)c0 * NK * 4096, y, partials);
        bn_fin_k<<<1, 128, 0, stream>>>(partials, gamma + c0 * 64, beta + c0 * 64, scsh);
        bn_relu_cast_k<<<appl_blocks, b256, 0, stream>>>(y, scsh, xb);
        conv_k<<<NB_CONV, b256, 0, stream>>>(xb, nbrs, Wp + (size_t)c1 * NK * 4096, y, partials);
        bn_fin_k<<<1, 128, 0, stream>>>(partials, gamma + c1 * 64, beta + c1 * 64, scsh);
        const float* res = (blk == 0) ? feats : (const float*)out;
        bn_add_relu_k<<<appl_blocks, b256, 0, stream>>>(y, scsh, res, out, xb, blk == 0 ? 1 : 0);
    }
}